// Round 5
// baseline (848.771 us; speedup 1.0000x reference)
//
#include <hip/hip_runtime.h>
#include <hip/hip_bf16.h>
#include <stdint.h>

#define SEQ    2048
#define HIDDEN 4096
#define INTER  11008

typedef short bf16x8 __attribute__((ext_vector_type(8)));
typedef float f32x4  __attribute__((ext_vector_type(4)));
typedef unsigned short u16x8 __attribute__((ext_vector_type(8)));

#define BAR()  asm volatile("s_barrier" ::: "memory")
#define WAIT6  asm volatile("s_waitcnt vmcnt(6)" ::: "memory")
#define WAIT4  asm volatile("s_waitcnt vmcnt(4)" ::: "memory")
#define WAIT0  asm volatile("s_waitcnt vmcnt(0)" ::: "memory")

__device__ __forceinline__ unsigned short f2bf(float f) {
    union { __hip_bfloat16 h; unsigned short u; } v;
    v.h = __float2bfloat16(f);
    return v.u;
}

__device__ __forceinline__ void gload_lds16(const void* g, void* lds) {
    __builtin_amdgcn_global_load_lds(
        (const __attribute__((address_space(1))) uint32_t*)g,
        (__attribute__((address_space(3))) uint32_t*)lds,
        16, 0, 0);
}

// ---------------------------------------------------------------------------
// x fp32 -> bf16
// ---------------------------------------------------------------------------
__global__ __launch_bounds__(256) void k_cvt_x(const float* __restrict__ x,
                                               unsigned short* __restrict__ xb) {
    int i = (blockIdx.x * 256 + threadIdx.x) * 4;
    float4 v = *(const float4*)(x + i);
    ushort4 o;
    o.x = f2bf(v.x); o.y = f2bf(v.y); o.z = f2bf(v.z); o.w = f2bf(v.w);
    *(ushort4*)(xb + i) = o;
}

// ---------------------------------------------------------------------------
// Weight dequant: int32 codes -> bf16. 8 codes/thread. group = i>>7.
// ---------------------------------------------------------------------------
__global__ __launch_bounds__(256) void k_dequant(
    const int* __restrict__ qw, const int* __restrict__ qz,
    const float* __restrict__ sc, unsigned short* __restrict__ w)
{
    size_t i = ((size_t)blockIdx.x * 256 + threadIdx.x) * 8;
    int gi = (int)(i >> 7);
    int   z = qz[gi];
    float s = sc[gi];
    float zs = -(float)z * s;
    int4 q0 = *(const int4*)(qw + i);
    int4 q1 = *(const int4*)(qw + i + 4);
    u16x8 o;
    o[0] = f2bf(fmaf((float)q0.x, s, zs));
    o[1] = f2bf(fmaf((float)q0.y, s, zs));
    o[2] = f2bf(fmaf((float)q0.z, s, zs));
    o[3] = f2bf(fmaf((float)q0.w, s, zs));
    o[4] = f2bf(fmaf((float)q1.x, s, zs));
    o[5] = f2bf(fmaf((float)q1.y, s, zs));
    o[6] = f2bf(fmaf((float)q1.z, s, zs));
    o[7] = f2bf(fmaf((float)q1.w, s, zs));
    *(u16x8*)(w + i) = o;
}

// ---------------------------------------------------------------------------
// Fused gate+up GEMM + SwiGLU -> h (bf16).
// 512 thr (8 waves: 2M x 4N). Tile 128x128, BK=64, double-buffered LDS (96KB).
// Counted vmcnt(6) + raw barriers: next tile's loads stay in flight under MFMA.
// Grid 1376; XCD swizzle (chunk 172) then M-adjacent decode for weight reuse.
// ---------------------------------------------------------------------------
__global__ __launch_bounds__(512) void k_gate_up(
    const unsigned short* __restrict__ xb,   // [SEQ][HIDDEN] bf16
    const unsigned short* __restrict__ wg,   // [INTER][HIDDEN] bf16
    const unsigned short* __restrict__ wu,   // [INTER][HIDDEN] bf16
    const float* __restrict__ gbias, const float* __restrict__ ubias,
    unsigned short* __restrict__ h)          // [SEQ][INTER] bf16
{
    __shared__ __align__(16) unsigned short A0[128 * 64], A1[128 * 64];
    __shared__ __align__(16) unsigned short Bg0[128 * 64], Bg1[128 * 64];
    __shared__ __align__(16) unsigned short Bu0[128 * 64], Bu1[128 * 64];

    const int orig = blockIdx.x;                  // 1376 = 8 * 172
    const int swz  = (orig & 7) * 172 + (orig >> 3);
    const int mt   = swz & 15;                    // M-siblings adjacent
    const int nt   = swz >> 4;
    const int m0   = mt * 128;
    const int n0   = nt * 128;

    const int t    = threadIdx.x;
    const int lane = t & 63;
    const int wave = t >> 6;
    const int wm = (wave >> 2) * 64;
    const int wn = (wave & 3) * 32;

    f32x4 accG[4][2], accU[4][2];
#pragma unroll
    for (int mi = 0; mi < 4; ++mi)
#pragma unroll
        for (int ni = 0; ni < 2; ++ni) {
            accG[mi][ni] = (f32x4){0.f, 0.f, 0.f, 0.f};
            accU[mi][ni] = (f32x4){0.f, 0.f, 0.f, 0.f};
        }

    auto stage = [&](unsigned short* At, unsigned short* Bgt, unsigned short* But,
                     int kt) {
        const int k0 = kt * 64;
#pragma unroll
        for (int cc = 0; cc < 2; ++cc) {
            int idx  = t + 512 * cc;
            int row  = idx >> 3;
            int scol = ((idx & 7) * 16) ^ ((row & 7) << 4);
            gload_lds16((const char*)(xb + (size_t)(m0 + row) * HIDDEN + k0) + scol,
                        (char*)At + idx * 16);
            gload_lds16((const char*)(wg + (size_t)(n0 + row) * HIDDEN + k0) + scol,
                        (char*)Bgt + idx * 16);
            gload_lds16((const char*)(wu + (size_t)(n0 + row) * HIDDEN + k0) + scol,
                        (char*)But + idx * 16);
        }
    };

    auto comp = [&](const unsigned short* At, const unsigned short* Bgt,
                    const unsigned short* But) {
#pragma unroll
        for (int kk = 0; kk < 2; ++kk) {
            bf16x8 af[4], bg[2], bu[2];
#pragma unroll
            for (int mi = 0; mi < 4; ++mi) {
                int row  = wm + mi * 16 + (lane & 15);
                int colb = kk * 64 + ((lane >> 4) * 16);
                af[mi] = *(const bf16x8*)((const char*)At + row * 128 +
                                          (colb ^ ((row & 7) << 4)));
            }
#pragma unroll
            for (int ni = 0; ni < 2; ++ni) {
                int row  = wn + ni * 16 + (lane & 15);
                int colb = kk * 64 + ((lane >> 4) * 16);
                int off  = row * 128 + (colb ^ ((row & 7) << 4));
                bg[ni] = *(const bf16x8*)((const char*)Bgt + off);
                bu[ni] = *(const bf16x8*)((const char*)But + off);
            }
            __builtin_amdgcn_s_setprio(1);
#pragma unroll
            for (int mi = 0; mi < 4; ++mi)
#pragma unroll
                for (int ni = 0; ni < 2; ++ni) {
                    accG[mi][ni] = __builtin_amdgcn_mfma_f32_16x16x32_bf16(
                        af[mi], bg[ni], accG[mi][ni], 0, 0, 0);
                    accU[mi][ni] = __builtin_amdgcn_mfma_f32_16x16x32_bf16(
                        af[mi], bu[ni], accU[mi][ni], 0, 0, 0);
                }
            __builtin_amdgcn_s_setprio(0);
        }
    };

    // NT = 64 K-tiles. Pipeline: stage(t+1) in flight while computing t.
    stage(A0, Bg0, Bu0, 0);
    for (int kt = 0; kt < 62; kt += 2) {
        stage(A1, Bg1, Bu1, kt + 1); WAIT6; BAR(); comp(A0, Bg0, Bu0); BAR();
        stage(A0, Bg0, Bu0, kt + 2); WAIT6; BAR(); comp(A1, Bg1, Bu1); BAR();
    }
    stage(A1, Bg1, Bu1, 63); WAIT6; BAR(); comp(A0, Bg0, Bu0); BAR();
    WAIT0; BAR(); comp(A1, Bg1, Bu1);

    // ---- epilogue: SwiGLU ----
#pragma unroll
    for (int ni = 0; ni < 2; ++ni) {
        int col = n0 + wn + ni * 16 + (lane & 15);
        float gb = gbias[col], ub = ubias[col];
#pragma unroll
        for (int mi = 0; mi < 4; ++mi) {
#pragma unroll
            for (int j = 0; j < 4; ++j) {
                int row = m0 + wm + mi * 16 + ((lane >> 4) * 4) + j;
                float g = accG[mi][ni][j] + gb;
                float u = accU[mi][ni][j] + ub;
                float sig = 1.f / (1.f + __expf(-g));
                h[(size_t)row * INTER + col] = f2bf(g * sig * u);
            }
        }
    }
}

// ---------------------------------------------------------------------------
// Down GEMM: y = h @ Wd^T + bias (fp32). 512 thr, tile 128x128, BK=64,
// double-buffered (64KB, 2 blocks/CU), counted vmcnt(4). Grid 512, XCD swz.
// ---------------------------------------------------------------------------
__global__ __launch_bounds__(512) void k_down(
    const unsigned short* __restrict__ h,    // [SEQ][INTER] bf16
    const unsigned short* __restrict__ wd,   // [HIDDEN][INTER] bf16
    const float* __restrict__ dbias,
    float* __restrict__ y)                   // [SEQ][HIDDEN] fp32
{
    __shared__ __align__(16) unsigned short A0[128 * 64], A1[128 * 64];
    __shared__ __align__(16) unsigned short B0[128 * 64], B1[128 * 64];

    const int orig = blockIdx.x;                  // 512 = 8 * 64
    const int swz  = (orig & 7) * 64 + (orig >> 3);
    const int mt   = swz & 15;
    const int nt   = swz >> 4;
    const int m0   = mt * 128;
    const int n0   = nt * 128;

    const int t    = threadIdx.x;
    const int lane = t & 63;
    const int wave = t >> 6;
    const int wm = (wave >> 2) * 64;
    const int wn = (wave & 3) * 32;

    f32x4 acc[4][2];
#pragma unroll
    for (int mi = 0; mi < 4; ++mi)
#pragma unroll
        for (int ni = 0; ni < 2; ++ni)
            acc[mi][ni] = (f32x4){0.f, 0.f, 0.f, 0.f};

    auto stage = [&](unsigned short* At, unsigned short* Bt, int kt) {
        const int k0 = kt * 64;
#pragma unroll
        for (int cc = 0; cc < 2; ++cc) {
            int idx  = t + 512 * cc;
            int row  = idx >> 3;
            int scol = ((idx & 7) * 16) ^ ((row & 7) << 4);
            gload_lds16((const char*)(h + (size_t)(m0 + row) * INTER + k0) + scol,
                        (char*)At + idx * 16);
            gload_lds16((const char*)(wd + (size_t)(n0 + row) * INTER + k0) + scol,
                        (char*)Bt + idx * 16);
        }
    };

    auto comp = [&](const unsigned short* At, const unsigned short* Bt) {
#pragma unroll
        for (int kk = 0; kk < 2; ++kk) {
            bf16x8 af[4], bd[2];
#pragma unroll
            for (int mi = 0; mi < 4; ++mi) {
                int row  = wm + mi * 16 + (lane & 15);
                int colb = kk * 64 + ((lane >> 4) * 16);
                af[mi] = *(const bf16x8*)((const char*)At + row * 128 +
                                          (colb ^ ((row & 7) << 4)));
            }
#pragma unroll
            for (int ni = 0; ni < 2; ++ni) {
                int row  = wn + ni * 16 + (lane & 15);
                int colb = kk * 64 + ((lane >> 4) * 16);
                bd[ni] = *(const bf16x8*)((const char*)Bt + row * 128 +
                                          (colb ^ ((row & 7) << 4)));
            }
            __builtin_amdgcn_s_setprio(1);
#pragma unroll
            for (int mi = 0; mi < 4; ++mi)
#pragma unroll
                for (int ni = 0; ni < 2; ++ni)
                    acc[mi][ni] = __builtin_amdgcn_mfma_f32_16x16x32_bf16(
                        af[mi], bd[ni], acc[mi][ni], 0, 0, 0);
            __builtin_amdgcn_s_setprio(0);
        }
    };

    // NT = 172 K-tiles (even).
    stage(A0, B0, 0);
    for (int kt = 0; kt < 170; kt += 2) {
        stage(A1, B1, kt + 1); WAIT4; BAR(); comp(A0, B0); BAR();
        stage(A0, B0, kt + 2); WAIT4; BAR(); comp(A1, B1); BAR();
    }
    stage(A1, B1, 171); WAIT4; BAR(); comp(A0, B0); BAR();
    WAIT0; BAR(); comp(A1, B1);

#pragma unroll
    for (int ni = 0; ni < 2; ++ni) {
        int col = n0 + wn + ni * 16 + (lane & 15);
        float db = dbias[col];
#pragma unroll
        for (int mi = 0; mi < 4; ++mi) {
#pragma unroll
            for (int j = 0; j < 4; ++j) {
                int row = m0 + wm + mi * 16 + ((lane >> 4) * 4) + j;
                y[(size_t)row * HIDDEN + col] = acc[mi][ni][j] + db;
            }
        }
    }
}

// ---------------------------------------------------------------------------
extern "C" void kernel_launch(void* const* d_in, const int* in_sizes, int n_in,
                              void* d_out, int out_size, void* d_ws, size_t ws_size,
                              hipStream_t stream) {
    const float* x    = (const float*)d_in[0];
    const int*   gqw  = (const int*)d_in[1];
    const int*   gqz  = (const int*)d_in[2];
    const float* gsc  = (const float*)d_in[3];
    const float* gbia = (const float*)d_in[4];
    const int*   uqw  = (const int*)d_in[5];
    const int*   uqz  = (const int*)d_in[6];
    const float* usc  = (const float*)d_in[7];
    const float* ubia = (const float*)d_in[8];
    const int*   dqw  = (const int*)d_in[9];
    const int*   dqz  = (const int*)d_in[10];
    const float* dsc  = (const float*)d_in[11];
    const float* dbia = (const float*)d_in[12];
    float* y = (float*)d_out;

    const size_t N_XB = (size_t)SEQ * HIDDEN;
    const size_t N_H  = (size_t)SEQ * INTER;
    const size_t N_W  = (size_t)INTER * HIDDEN;

    unsigned short* xb  = (unsigned short*)d_ws;
    unsigned short* hh  = xb + N_XB;
    unsigned short* wgb = hh + N_H;
    unsigned short* wub = wgb + N_W;
    unsigned short* wdb = wgb;                 // reused after k_gate_up

    const int dq_blocks = (int)(N_W / 2048);   // 22016

    k_cvt_x<<<(SEQ * HIDDEN) / 1024, 256, 0, stream>>>(x, xb);
    k_dequant<<<dq_blocks, 256, 0, stream>>>(gqw, gqz, gsc, wgb);
    k_dequant<<<dq_blocks, 256, 0, stream>>>(uqw, uqz, usc, wub);
    k_gate_up<<<dim3(1376), 512, 0, stream>>>(xb, wgb, wub, gbia, ubia, hh);
    k_dequant<<<dq_blocks, 256, 0, stream>>>(dqw, dqz, dsc, wdb);
    k_down<<<dim3(512), 512, 0, stream>>>(hh, wdb, dbia, y);
}

// Round 6
// 845.918 us; speedup vs baseline: 1.0034x; 1.0034x over previous
//
#include <hip/hip_runtime.h>
#include <hip/hip_bf16.h>
#include <stdint.h>

#define SEQ    2048
#define HIDDEN 4096
#define INTER  11008

typedef short bf16x8 __attribute__((ext_vector_type(8)));
typedef float f32x4  __attribute__((ext_vector_type(4)));
typedef unsigned short u16x8 __attribute__((ext_vector_type(8)));

__device__ __forceinline__ unsigned short f2bf(float f) {
    union { __hip_bfloat16 h; unsigned short u; } v;
    v.h = __float2bfloat16(f);
    return v.u;
}

__device__ __forceinline__ void gload_lds16(const void* g, void* lds) {
    __builtin_amdgcn_global_load_lds(
        (const __attribute__((address_space(1))) uint32_t*)g,
        (__attribute__((address_space(3))) uint32_t*)lds,
        16, 0, 0);
}

// ---------------------------------------------------------------------------
// x fp32 -> bf16
// ---------------------------------------------------------------------------
__global__ __launch_bounds__(256) void k_cvt_x(const float* __restrict__ x,
                                               unsigned short* __restrict__ xb) {
    int i = (blockIdx.x * 256 + threadIdx.x) * 4;
    float4 v = *(const float4*)(x + i);
    ushort4 o;
    o.x = f2bf(v.x); o.y = f2bf(v.y); o.z = f2bf(v.z); o.w = f2bf(v.w);
    *(ushort4*)(xb + i) = o;
}

// ---------------------------------------------------------------------------
// Weight dequant: int32 codes -> bf16. 8 codes/thread. group = i>>7.
// ---------------------------------------------------------------------------
__global__ __launch_bounds__(256) void k_dequant(
    const int* __restrict__ qw, const int* __restrict__ qz,
    const float* __restrict__ sc, unsigned short* __restrict__ w)
{
    size_t i = ((size_t)blockIdx.x * 256 + threadIdx.x) * 8;
    int gi = (int)(i >> 7);
    int   z = qz[gi];
    float s = sc[gi];
    float zs = -(float)z * s;
    int4 q0 = *(const int4*)(qw + i);
    int4 q1 = *(const int4*)(qw + i + 4);
    u16x8 o;
    o[0] = f2bf(fmaf((float)q0.x, s, zs));
    o[1] = f2bf(fmaf((float)q0.y, s, zs));
    o[2] = f2bf(fmaf((float)q0.z, s, zs));
    o[3] = f2bf(fmaf((float)q0.w, s, zs));
    o[4] = f2bf(fmaf((float)q1.x, s, zs));
    o[5] = f2bf(fmaf((float)q1.y, s, zs));
    o[6] = f2bf(fmaf((float)q1.z, s, zs));
    o[7] = f2bf(fmaf((float)q1.w, s, zs));
    *(u16x8*)(w + i) = o;
}

// ---------------------------------------------------------------------------
// Fused gate+up GEMM + SwiGLU -> h (bf16).
// 512 thr (8 waves: 4M x 2N). Block tile 256(M) x 128(N), BK=64, single-buf
// 64KB LDS (2 blocks/CU). Wave tile 64M x 64N for BOTH gate and up:
// per kk reads 12 frags for 32 MFMA -> 0.031 LDS-B/flop (round-4 was 0.042).
// Grid 688 = 8 Mtiles x 86 Ntiles; mt = bid & 7 (M-siblings adjacent).
// ---------------------------------------------------------------------------
__global__ __launch_bounds__(512) void k_gate_up(
    const unsigned short* __restrict__ xb,   // [SEQ][HIDDEN] bf16
    const unsigned short* __restrict__ wg,   // [INTER][HIDDEN] bf16
    const unsigned short* __restrict__ wu,   // [INTER][HIDDEN] bf16
    const float* __restrict__ gbias, const float* __restrict__ ubias,
    unsigned short* __restrict__ h)          // [SEQ][INTER] bf16
{
    __shared__ __align__(16) unsigned short At[256 * 64]; // 32 KB, swizzled
    __shared__ __align__(16) unsigned short Bg[128 * 64]; // 16 KB, swizzled
    __shared__ __align__(16) unsigned short Bu[128 * 64]; // 16 KB, swizzled

    const int bid = blockIdx.x;          // 688 = 8 * 86
    const int mt  = bid & 7;             // M-siblings adjacent
    const int nt  = bid >> 3;
    const int m0  = mt * 256;
    const int n0  = nt * 128;

    const int t    = threadIdx.x;
    const int lane = t & 63;
    const int wave = t >> 6;
    const int wm = (wave >> 1) * 64;     // 0..192
    const int wn = (wave & 1) * 64;      // 0,64

    f32x4 accG[4][4], accU[4][4];
#pragma unroll
    for (int mi = 0; mi < 4; ++mi)
#pragma unroll
        for (int ni = 0; ni < 4; ++ni) {
            accG[mi][ni] = (f32x4){0.f, 0.f, 0.f, 0.f};
            accU[mi][ni] = (f32x4){0.f, 0.f, 0.f, 0.f};
        }

    for (int kt = 0; kt < HIDDEN / 64; ++kt) {
        const int k0 = kt * 64;

        // ---- stage A (256x64) : 2048 chunks, 4/thread ----
#pragma unroll
        for (int cc = 0; cc < 4; ++cc) {
            int idx  = t + 512 * cc;
            int row  = idx >> 3;
            int scol = ((idx & 7) * 16) ^ ((row & 7) << 4);
            gload_lds16((const char*)(xb + (size_t)(m0 + row) * HIDDEN + k0) + scol,
                        (char*)At + idx * 16);
        }
        // ---- stage Bg, Bu (128x64 each): 1024 chunks, 2/thread each ----
#pragma unroll
        for (int cc = 0; cc < 2; ++cc) {
            int idx  = t + 512 * cc;
            int row  = idx >> 3;
            int scol = ((idx & 7) * 16) ^ ((row & 7) << 4);
            gload_lds16((const char*)(wg + (size_t)(n0 + row) * HIDDEN + k0) + scol,
                        (char*)Bg + idx * 16);
            gload_lds16((const char*)(wu + (size_t)(n0 + row) * HIDDEN + k0) + scol,
                        (char*)Bu + idx * 16);
        }

        __syncthreads();

#pragma unroll
        for (int kk = 0; kk < 2; ++kk) {
            bf16x8 af[4], bg[4], bu[4];
            int colb = kk * 64 + ((lane >> 4) * 16);
#pragma unroll
            for (int mi = 0; mi < 4; ++mi) {
                int row = wm + mi * 16 + (lane & 15);
                af[mi] = *(const bf16x8*)((const char*)At + row * 128 +
                                          (colb ^ ((row & 7) << 4)));
            }
#pragma unroll
            for (int ni = 0; ni < 4; ++ni) {
                int row = wn + ni * 16 + (lane & 15);
                int off = row * 128 + (colb ^ ((row & 7) << 4));
                bg[ni] = *(const bf16x8*)((const char*)Bg + off);
                bu[ni] = *(const bf16x8*)((const char*)Bu + off);
            }
            __builtin_amdgcn_s_setprio(1);
#pragma unroll
            for (int mi = 0; mi < 4; ++mi)
#pragma unroll
                for (int ni = 0; ni < 4; ++ni) {
                    accG[mi][ni] = __builtin_amdgcn_mfma_f32_16x16x32_bf16(
                        af[mi], bg[ni], accG[mi][ni], 0, 0, 0);
                    accU[mi][ni] = __builtin_amdgcn_mfma_f32_16x16x32_bf16(
                        af[mi], bu[ni], accU[mi][ni], 0, 0, 0);
                }
            __builtin_amdgcn_s_setprio(0);
        }

        __syncthreads();
    }

    // ---- epilogue: SwiGLU ----
#pragma unroll
    for (int ni = 0; ni < 4; ++ni) {
        int col = n0 + wn + ni * 16 + (lane & 15);
        float gb = gbias[col], ub = ubias[col];
#pragma unroll
        for (int mi = 0; mi < 4; ++mi) {
#pragma unroll
            for (int j = 0; j < 4; ++j) {
                int row = m0 + wm + mi * 16 + ((lane >> 4) * 4) + j;
                float g = accG[mi][ni][j] + gb;
                float u = accU[mi][ni][j] + ub;
                float sig = 1.f / (1.f + __expf(-g));
                h[(size_t)row * INTER + col] = f2bf(g * sig * u);
            }
        }
    }
}

// ---------------------------------------------------------------------------
// Down GEMM: y = h @ Wd^T + bias (fp32 out). 512 thr, tile 128x128, BK=64.
// Round-4 proven structure, unchanged.
// ---------------------------------------------------------------------------
__global__ __launch_bounds__(512) void k_down(
    const unsigned short* __restrict__ h,    // [SEQ][INTER] bf16
    const unsigned short* __restrict__ wd,   // [HIDDEN][INTER] bf16
    const float* __restrict__ dbias,
    float* __restrict__ y)                   // [SEQ][HIDDEN] fp32
{
    __shared__ __align__(16) unsigned short At[128 * 64]; // 16 KB
    __shared__ __align__(16) unsigned short Bd[128 * 64]; // 16 KB

    const int bid = blockIdx.x;
    const int mt  = bid & 15;
    const int nt  = bid >> 4;
    const int m0  = mt * 128;
    const int n0  = nt * 128;

    const int t    = threadIdx.x;
    const int lane = t & 63;
    const int wave = t >> 6;
    const int wm = (wave >> 2) * 64;
    const int wn = (wave & 3) * 32;

    f32x4 acc[4][2];
#pragma unroll
    for (int mi = 0; mi < 4; ++mi)
#pragma unroll
        for (int ni = 0; ni < 2; ++ni)
            acc[mi][ni] = (f32x4){0.f, 0.f, 0.f, 0.f};

    for (int kt = 0; kt < INTER / 64; ++kt) {
        const int k0 = kt * 64;

#pragma unroll
        for (int cc = 0; cc < 2; ++cc) {
            int idx  = t + 512 * cc;
            int row  = idx >> 3;
            int scol = ((idx & 7) * 16) ^ ((row & 7) << 4);
            gload_lds16((const char*)(h + (size_t)(m0 + row) * INTER + k0) + scol,
                        (char*)At + idx * 16);
            gload_lds16((const char*)(wd + (size_t)(n0 + row) * INTER + k0) + scol,
                        (char*)Bd + idx * 16);
        }

        __syncthreads();

#pragma unroll
        for (int kk = 0; kk < 2; ++kk) {
            bf16x8 af[4], bd[2];
#pragma unroll
            for (int mi = 0; mi < 4; ++mi) {
                int row  = wm + mi * 16 + (lane & 15);
                int colb = kk * 64 + ((lane >> 4) * 16);
                af[mi] = *(const bf16x8*)((const char*)At + row * 128 +
                                          (colb ^ ((row & 7) << 4)));
            }
#pragma unroll
            for (int ni = 0; ni < 2; ++ni) {
                int row  = wn + ni * 16 + (lane & 15);
                int colb = kk * 64 + ((lane >> 4) * 16);
                bd[ni] = *(const bf16x8*)((const char*)Bd + row * 128 +
                                          (colb ^ ((row & 7) << 4)));
            }
            __builtin_amdgcn_s_setprio(1);
#pragma unroll
            for (int mi = 0; mi < 4; ++mi)
#pragma unroll
                for (int ni = 0; ni < 2; ++ni)
                    acc[mi][ni] = __builtin_amdgcn_mfma_f32_16x16x32_bf16(
                        af[mi], bd[ni], acc[mi][ni], 0, 0, 0);
            __builtin_amdgcn_s_setprio(0);
        }

        __syncthreads();
    }

#pragma unroll
    for (int ni = 0; ni < 2; ++ni) {
        int col = n0 + wn + ni * 16 + (lane & 15);
        float db = dbias[col];
#pragma unroll
        for (int mi = 0; mi < 4; ++mi) {
#pragma unroll
            for (int j = 0; j < 4; ++j) {
                int row = m0 + wm + mi * 16 + ((lane >> 4) * 4) + j;
                y[(size_t)row * HIDDEN + col] = acc[mi][ni][j] + db;
            }
        }
    }
}

// ---------------------------------------------------------------------------
extern "C" void kernel_launch(void* const* d_in, const int* in_sizes, int n_in,
                              void* d_out, int out_size, void* d_ws, size_t ws_size,
                              hipStream_t stream) {
    const float* x    = (const float*)d_in[0];
    const int*   gqw  = (const int*)d_in[1];
    const int*   gqz  = (const int*)d_in[2];
    const float* gsc  = (const float*)d_in[3];
    const float* gbia = (const float*)d_in[4];
    const int*   uqw  = (const int*)d_in[5];
    const int*   uqz  = (const int*)d_in[6];
    const float* usc  = (const float*)d_in[7];
    const float* ubia = (const float*)d_in[8];
    const int*   dqw  = (const int*)d_in[9];
    const int*   dqz  = (const int*)d_in[10];
    const float* dsc  = (const float*)d_in[11];
    const float* dbia = (const float*)d_in[12];
    float* y = (float*)d_out;

    const size_t N_XB = (size_t)SEQ * HIDDEN;
    const size_t N_H  = (size_t)SEQ * INTER;
    const size_t N_W  = (size_t)INTER * HIDDEN;

    unsigned short* xb  = (unsigned short*)d_ws;
    unsigned short* hh  = xb + N_XB;
    unsigned short* wgb = hh + N_H;
    unsigned short* wub = wgb + N_W;
    unsigned short* wdb = wgb;                 // reused after k_gate_up

    const int dq_blocks = (int)(N_W / 2048);   // 22016

    k_cvt_x<<<(SEQ * HIDDEN) / 1024, 256, 0, stream>>>(x, xb);
    k_dequant<<<dq_blocks, 256, 0, stream>>>(gqw, gqz, gsc, wgb);
    k_dequant<<<dq_blocks, 256, 0, stream>>>(uqw, uqz, usc, wub);
    k_gate_up<<<dim3(688), 512, 0, stream>>>(xb, wgb, wub, gbia, ubia, hh);
    k_dequant<<<dq_blocks, 256, 0, stream>>>(dqw, dqz, dsc, wdb);
    k_down<<<dim3(512), 512, 0, stream>>>(hh, wdb, dbia, y);
}